// Round 8
// baseline (580.805 us; speedup 1.0000x reference)
//
#include <hip/hip_runtime.h>

#define NPILLARS 96000
#define MPTS 32
#define NCHAN 64
#define NXC 432
#define NYC 496
#define NB 8
#define NCELLS (NXC*NYC)          // 214272
#define PL4 (NCELLS/4)            // 53568 natf4 per plane; 53568 % 64 == 0
#define NBLK 1024                 // k_fused grid (must match launch)
#define PXc 0.16f
#define PYc 0.16f
#define PZc 4.0f
#define XOFF (0.08f)              // PX/2 + X0
#define YOFF (0.08f - 39.68f)     // PY/2 + Y0
#define ZOFF (2.0f - 3.0f)        // PZ/2 + Z0
#define BN_EPS 1e-3f

typedef __attribute__((ext_vector_type(8))) short short8;
typedef __attribute__((ext_vector_type(16))) float float16;
typedef __attribute__((ext_vector_type(4))) float natf4;

__device__ __forceinline__ int f2bf(float x) {
    union { float f; unsigned u; } v; v.f = x;
    unsigned r = v.u + 0x7FFFu + ((v.u >> 16) & 1u);  // RNE
    return (int)(r >> 16);
}

// Upper-triangle pair list: Q(flat_idx, i, j) for 0<=i<=j<10 (row-major).
#define PAIRS(Q) \
 Q(0,0,0) Q(1,0,1) Q(2,0,2) Q(3,0,3) Q(4,0,4) Q(5,0,5) Q(6,0,6) Q(7,0,7) Q(8,0,8) Q(9,0,9) \
 Q(10,1,1) Q(11,1,2) Q(12,1,3) Q(13,1,4) Q(14,1,5) Q(15,1,6) Q(16,1,7) Q(17,1,8) Q(18,1,9) \
 Q(19,2,2) Q(20,2,3) Q(21,2,4) Q(22,2,5) Q(23,2,6) Q(24,2,7) Q(25,2,8) Q(26,2,9) \
 Q(27,3,3) Q(28,3,4) Q(29,3,5) Q(30,3,6) Q(31,3,7) Q(32,3,8) Q(33,3,9) \
 Q(34,4,4) Q(35,4,5) Q(36,4,6) Q(37,4,7) Q(38,4,8) Q(39,4,9) \
 Q(40,5,5) Q(41,5,6) Q(42,5,7) Q(43,5,8) Q(44,5,9) \
 Q(45,6,6) Q(46,6,7) Q(47,6,8) Q(48,6,9) \
 Q(49,7,7) Q(50,7,8) Q(51,7,9) \
 Q(52,8,8) Q(53,8,9) \
 Q(54,9,9)

// Fused pass (unchanged from R7): TWO pillars per wave, moments counted once,
// raw max_m(h) via 4x MFMA 32x32x16, winner p+1, moments -> 65 atomicAdds.
__global__ __launch_bounds__(256, 3)
void k_fused(const float4* __restrict__ pillars,
             const int4* __restrict__ coords,
             const int* __restrict__ num_points,
             const float* __restrict__ W,
             float* __restrict__ pvmax,     // [NPILLARS][64] raw max_m h
             float* __restrict__ mom,       // [65] global moments (pre-zeroed)
             int* __restrict__ winner) {
    const int tid  = threadIdx.x;
    const int lane = tid & 63;
    const int sub  = lane & 31;
    const int half = lane >> 5;
    const int wv   = tid >> 6;
    const int wid    = (blockIdx.x * blockDim.x + tid) >> 6;
    const int nwaves = (gridDim.x * blockDim.x) >> 6;

    short8 bf0, bf1;
#pragma unroll
    for (int r = 0; r < 8; r++) {
        const int k = half * 8 + r;
        bf0[r] = (k < 10) ? (short)f2bf(W[k * NCHAN + sub])      : (short)0;
        bf1[r] = (k < 10) ? (short)f2bf(W[k * NCHAN + 32 + sub]) : (short)0;
    }

    float s0=0.f,s1=0.f,s2=0.f,s3=0.f,s4=0.f,s5=0.f,s6=0.f,s7=0.f,s8=0.f,s9=0.f;
#define QDECL(idx,i,j) float q_##i##_##j = 0.f;
    PAIRS(QDECL)
#undef QDECL

    for (int base = wid * 2; base < NPILLARS; base += nwaves * 2) {
        const int p = base + half;
        float4 pt = pillars[p * MPTS + sub];
        float sx = pt.x, sy = pt.y, sz = pt.z;
#pragma unroll
        for (int m = 16; m >= 1; m >>= 1) {
            sx += __shfl_xor(sx, m);
            sy += __shfl_xor(sy, m);
            sz += __shfl_xor(sz, m);
        }
        const float n = (float)num_points[p];
        const float mx = sx / n, my = sy / n, mz = sz / n;
        const int4  cd = coords[p];
        const float ctx = (float)cd.w * PXc + XOFF;
        const float cty = (float)cd.z * PYc + YOFF;
        const float ctz = (float)cd.y * PZc + ZOFF;
        const float f0=pt.x, f1=pt.y, f2=pt.z, f3=pt.w;
        const float f4=pt.x-mx,  f5=pt.y-my,  f6=pt.z-mz;
        const float f7=pt.x-ctx, f8=pt.y-cty, f9=pt.z-ctz;
        s0+=f0; s1+=f1; s2+=f2; s3+=f3; s4+=f4;
        s5+=f5; s6+=f6; s7+=f7; s8+=f8; s9+=f9;
#define QACC(idx,i,j) q_##i##_##j = fmaf(f##i, f##j, q_##i##_##j);
        PAIRS(QACC)
#undef QACC
        const int b0 = f2bf(f0), b1 = f2bf(f1), b2 = f2bf(f2), b3 = f2bf(f3),
                  b4 = f2bf(f4), b5 = f2bf(f5), b6 = f2bf(f6), b7 = f2bf(f7),
                  b8 = f2bf(f8), b9 = f2bf(f9);
        const int s8b = __shfl(b8, sub),      s9b = __shfl(b9, sub);
        const int t0 = __shfl(b0, sub + 32), t1 = __shfl(b1, sub + 32),
                  t2 = __shfl(b2, sub + 32), t3 = __shfl(b3, sub + 32),
                  t4 = __shfl(b4, sub + 32), t5 = __shfl(b5, sub + 32),
                  t6 = __shfl(b6, sub + 32), t7 = __shfl(b7, sub + 32);
        short8 a0v;
        a0v[0] = (short)(half ? s8b : b0);
        a0v[1] = (short)(half ? s9b : b1);
        a0v[2] = half ? (short)0 : (short)b2;
        a0v[3] = half ? (short)0 : (short)b3;
        a0v[4] = half ? (short)0 : (short)b4;
        a0v[5] = half ? (short)0 : (short)b5;
        a0v[6] = half ? (short)0 : (short)b6;
        a0v[7] = half ? (short)0 : (short)b7;
        short8 a1v;
        a1v[0] = (short)(half ? b8 : t0);
        a1v[1] = (short)(half ? b9 : t1);
        a1v[2] = half ? (short)0 : (short)t2;
        a1v[3] = half ? (short)0 : (short)t3;
        a1v[4] = half ? (short)0 : (short)t4;
        a1v[5] = half ? (short)0 : (short)t5;
        a1v[6] = half ? (short)0 : (short)t6;
        a1v[7] = half ? (short)0 : (short)t7;
        float16 accA0 = {}, accA1 = {}, accB0 = {}, accB1 = {};
        accA0 = __builtin_amdgcn_mfma_f32_32x32x16_bf16(a0v, bf0, accA0, 0, 0, 0);
        accA1 = __builtin_amdgcn_mfma_f32_32x32x16_bf16(a0v, bf1, accA1, 0, 0, 0);
        accB0 = __builtin_amdgcn_mfma_f32_32x32x16_bf16(a1v, bf0, accB0, 0, 0, 0);
        accB1 = __builtin_amdgcn_mfma_f32_32x32x16_bf16(a1v, bf1, accB1, 0, 0, 0);
        float mA0 = -3.4e38f, mA1 = -3.4e38f, mB0 = -3.4e38f, mB1 = -3.4e38f;
#pragma unroll
        for (int r = 0; r < 16; r++) {
            mA0 = fmaxf(mA0, accA0[r]);  mA1 = fmaxf(mA1, accA1[r]);
            mB0 = fmaxf(mB0, accB0[r]);  mB1 = fmaxf(mB1, accB1[r]);
        }
        mA0 = fmaxf(mA0, __shfl_xor(mA0, 32));  mA1 = fmaxf(mA1, __shfl_xor(mA1, 32));
        mB0 = fmaxf(mB0, __shfl_xor(mB0, 32));  mB1 = fmaxf(mB1, __shfl_xor(mB1, 32));
        pvmax[base * NCHAN + lane]       = half ? mA1 : mA0;
        pvmax[(base + 1) * NCHAN + lane] = half ? mB1 : mB0;
        if (sub == 0) {
            const int cell = cd.y + cd.z * NXC + cd.w;
            atomicMax(&winner[cd.x * NCELLS + cell], p + 1);   // 0 = empty
        }
    }

    __shared__ float lds_part[4][65];
#define RED6(v) { v += __shfl_xor(v,32); v += __shfl_xor(v,16); v += __shfl_xor(v,8); \
                  v += __shfl_xor(v,4);  v += __shfl_xor(v,2);  v += __shfl_xor(v,1); }
    RED6(s0) RED6(s1) RED6(s2) RED6(s3) RED6(s4)
    RED6(s5) RED6(s6) RED6(s7) RED6(s8) RED6(s9)
#define QRED(idx,i,j) RED6(q_##i##_##j)
    PAIRS(QRED)
#undef QRED
#undef RED6
    if (lane == 0) {
        float* dst = &lds_part[wv][0];
        dst[0]=s0; dst[1]=s1; dst[2]=s2; dst[3]=s3; dst[4]=s4;
        dst[5]=s5; dst[6]=s6; dst[7]=s7; dst[8]=s8; dst[9]=s9;
#define QST(idx,i,j) dst[10+idx] = q_##i##_##j;
        PAIRS(QST)
#undef QST
    }
    __syncthreads();
    if (tid < 65) {
        const float acc = lds_part[0][tid] + lds_part[1][tid]
                        + lds_part[2][tid] + lds_part[3][tid];
        atomicAdd(&mom[tid], acc);
    }
}

// Tiny: fold moments through W -> per-channel scale/shift (once, 64 threads).
__global__ void k_ss(const float* __restrict__ mom,
                     const float* __restrict__ W,
                     const float* __restrict__ gamma,
                     const float* __restrict__ beta,
                     float* __restrict__ ss) {
    const int c = threadIdx.x;  // 0..63
    const float invN = 1.0f / ((float)NPILLARS * (float)MPTS);
    float wv0=W[0*NCHAN+c], wv1=W[1*NCHAN+c], wv2=W[2*NCHAN+c], wv3=W[3*NCHAN+c],
          wv4=W[4*NCHAN+c], wv5=W[5*NCHAN+c], wv6=W[6*NCHAN+c], wv7=W[7*NCHAN+c],
          wv8=W[8*NCHAN+c], wv9=W[9*NCHAN+c];
    float mu = mom[0]*wv0 + mom[1]*wv1 + mom[2]*wv2 + mom[3]*wv3 + mom[4]*wv4
             + mom[5]*wv5 + mom[6]*wv6 + mom[7]*wv7 + mom[8]*wv8 + mom[9]*wv9;
    mu *= invN;
    float e2 = 0.f;
#define QFOLD(idx,i,j) { float tt = mom[10+idx] * wv##i * wv##j; \
                         e2 += (i == j) ? tt : 2.0f * tt; }
    PAIRS(QFOLD)
#undef QFOLD
    e2 *= invN;
    const float var = e2 - mu * mu;
    const float scale = gamma[c] * rsqrtf(var + BN_EPS);
    ss[c] = scale;
    ss[64 + c] = beta[c] - mu * scale;
}

// Expand: thread i writes out4[i] — ONE linear sweep of the 438 MB output
// (the fill-kernel pattern). PL4 % 64 == 0 -> waves never straddle planes:
// ss loads wave-uniform, winner int4 loads coalesced. Winner b-slice (857 KB)
// and pv lines get L2 reuse across the 64-plane sweep.
__global__ void k_expand(const int* __restrict__ winner,
                         const float* __restrict__ pvmax,
                         const float* __restrict__ ss,
                         float* __restrict__ out) {
    const int idx = blockIdx.x * blockDim.x + threadIdx.x;   // natf4 index in out
    const int plane = idx / PL4;            // b*64 + c  (magic-mul)
    const int cg    = idx - plane * PL4;    // cell group within plane
    const int b = plane >> 6, c = plane & 63;
    const float sc = ss[c], sh = ss[64 + c];
    const int4 w = ((const int4*)(winner + b * NCELLS))[cg];
    const float mk0 = (w.x > 0) ? 1.f : 0.f;
    const float mk1 = (w.y > 0) ? 1.f : 0.f;
    const float mk2 = (w.z > 0) ? 1.f : 0.f;
    const float mk3 = (w.w > 0) ? 1.f : 0.f;
    const size_t r0 = (size_t)((w.x > 0) ? w.x - 1 : 0) * NCHAN + c;
    const size_t r1 = (size_t)((w.y > 0) ? w.y - 1 : 0) * NCHAN + c;
    const size_t r2 = (size_t)((w.z > 0) ? w.z - 1 : 0) * NCHAN + c;
    const size_t r3 = (size_t)((w.w > 0) ? w.w - 1 : 0) * NCHAN + c;
    natf4 v;
    v.x = mk0 * fmaxf(0.f, fmaf(pvmax[r0], sc, sh));
    v.y = mk1 * fmaxf(0.f, fmaf(pvmax[r1], sc, sh));
    v.z = mk2 * fmaxf(0.f, fmaf(pvmax[r2], sc, sh));
    v.w = mk3 * fmaxf(0.f, fmaf(pvmax[r3], sc, sh));
    ((natf4*)out)[idx] = v;
}

extern "C" void kernel_launch(void* const* d_in, const int* in_sizes, int n_in,
                              void* d_out, int out_size, void* d_ws, size_t ws_size,
                              hipStream_t stream) {
    const float4* pillars    = (const float4*)d_in[0];
    const int4*   coords     = (const int4*)d_in[1];
    const int*    num_points = (const int*)d_in[2];
    const float*  W          = (const float*)d_in[3];
    const float*  gamma      = (const float*)d_in[4];
    const float*  beta       = (const float*)d_in[5];
    float* out = (float*)d_out;

    char* ws = (char*)d_ws;
    const size_t WIN_BYTES = (size_t)NB * NCELLS * sizeof(int);        // 6.86 MB
    float* mom    = (float*)ws;                        // 65 floats (zeroed below)
    float* ss     = (float*)(ws + 256);                // 128 floats
    int*   winner = (int*)(ws + 1024);                 // zeroed below (0 = empty)
    float* pvmax  = (float*)(ws + 1024 + WIN_BYTES);   // 24.6 MB

    // One memset covers mom + winner (winner encoding p+1 makes 0 = empty).
    (void)hipMemsetAsync(ws, 0, 1024 + WIN_BYTES, stream);

    k_fused <<<NBLK, 256, 0, stream>>>(pillars, coords, num_points, W,
                                       pvmax, mom, winner);
    k_ss    <<<1, 64, 0, stream>>>(mom, W, gamma, beta, ss);
    // total natf4 = NB*NCHAN*PL4 = 27,426,816 ; /256 = 107,136 blocks exactly
    k_expand<<<(NB * NCHAN * PL4) / 256, 256, 0, stream>>>(winner, pvmax, ss, out);
}

// Round 9
// 559.134 us; speedup vs baseline: 1.0388x; 1.0388x over previous
//
#include <hip/hip_runtime.h>

#define NPILLARS 96000
#define MPTS 32
#define NCHAN 64
#define NXC 432
#define NYC 496
#define NB 8
#define NCELLS (NXC*NYC)          // 214272
#define NBLK 1024                 // k_fused grid (must match launch)
#define PXc 0.16f
#define PYc 0.16f
#define PZc 4.0f
#define XOFF (0.08f)              // PX/2 + X0
#define YOFF (0.08f - 39.68f)     // PY/2 + Y0
#define ZOFF (2.0f - 3.0f)        // PZ/2 + Z0
#define BN_EPS 1e-3f

typedef __attribute__((ext_vector_type(8))) short short8;
typedef __attribute__((ext_vector_type(16))) float float16;
typedef __attribute__((ext_vector_type(4))) float natf4;

__device__ __forceinline__ int f2bf(float x) {
    union { float f; unsigned u; } v; v.f = x;
    unsigned r = v.u + 0x7FFFu + ((v.u >> 16) & 1u);  // RNE
    return (int)(r >> 16);
}

// Upper-triangle pair list: Q(flat_idx, i, j) for 0<=i<=j<10 (row-major).
#define PAIRS(Q) \
 Q(0,0,0) Q(1,0,1) Q(2,0,2) Q(3,0,3) Q(4,0,4) Q(5,0,5) Q(6,0,6) Q(7,0,7) Q(8,0,8) Q(9,0,9) \
 Q(10,1,1) Q(11,1,2) Q(12,1,3) Q(13,1,4) Q(14,1,5) Q(15,1,6) Q(16,1,7) Q(17,1,8) Q(18,1,9) \
 Q(19,2,2) Q(20,2,3) Q(21,2,4) Q(22,2,5) Q(23,2,6) Q(24,2,7) Q(25,2,8) Q(26,2,9) \
 Q(27,3,3) Q(28,3,4) Q(29,3,5) Q(30,3,6) Q(31,3,7) Q(32,3,8) Q(33,3,9) \
 Q(34,4,4) Q(35,4,5) Q(36,4,6) Q(37,4,7) Q(38,4,8) Q(39,4,9) \
 Q(40,5,5) Q(41,5,6) Q(42,5,7) Q(43,5,8) Q(44,5,9) \
 Q(45,6,6) Q(46,6,7) Q(47,6,8) Q(48,6,9) \
 Q(49,7,7) Q(50,7,8) Q(51,7,9) \
 Q(52,8,8) Q(53,8,9) \
 Q(54,9,9)

// Fused pass: TWO pillars per wave, moments counted once, raw max_m(h) via
// 4x MFMA 32x32x16, winner p+1. Moments exit as NON-ATOMIC per-block partials
// (partial[65][NBLK]) — no device-scope atomic RMW tail.
__global__ __launch_bounds__(256, 3)
void k_fused(const float4* __restrict__ pillars,
             const int4* __restrict__ coords,
             const int* __restrict__ num_points,
             const float* __restrict__ W,
             float* __restrict__ pvmax,     // [NPILLARS][64] raw max_m h
             float* __restrict__ partial,   // [65][NBLK] moment partials
             int* __restrict__ winner) {
    const int tid  = threadIdx.x;
    const int lane = tid & 63;
    const int sub  = lane & 31;
    const int half = lane >> 5;
    const int wv   = tid >> 6;
    const int wid    = (blockIdx.x * blockDim.x + tid) >> 6;
    const int nwaves = (gridDim.x * blockDim.x) >> 6;

    short8 bf0, bf1;
#pragma unroll
    for (int r = 0; r < 8; r++) {
        const int k = half * 8 + r;
        bf0[r] = (k < 10) ? (short)f2bf(W[k * NCHAN + sub])      : (short)0;
        bf1[r] = (k < 10) ? (short)f2bf(W[k * NCHAN + 32 + sub]) : (short)0;
    }

    float s0=0.f,s1=0.f,s2=0.f,s3=0.f,s4=0.f,s5=0.f,s6=0.f,s7=0.f,s8=0.f,s9=0.f;
#define QDECL(idx,i,j) float q_##i##_##j = 0.f;
    PAIRS(QDECL)
#undef QDECL

    for (int base = wid * 2; base < NPILLARS; base += nwaves * 2) {
        const int p = base + half;             // NPILLARS even -> always valid
        float4 pt = pillars[p * MPTS + sub];   // distinct pillar per half
        float sx = pt.x, sy = pt.y, sz = pt.z;
#pragma unroll
        for (int m = 16; m >= 1; m >>= 1) {    // masks <32: stays within each half
            sx += __shfl_xor(sx, m);
            sy += __shfl_xor(sy, m);
            sz += __shfl_xor(sz, m);
        }
        const float n = (float)num_points[p];
        const float mx = sx / n, my = sy / n, mz = sz / n;
        const int4  cd = coords[p];
        const float ctx = (float)cd.w * PXc + XOFF;
        const float cty = (float)cd.z * PYc + YOFF;
        const float ctz = (float)cd.y * PZc + ZOFF;
        const float f0=pt.x, f1=pt.y, f2=pt.z, f3=pt.w;
        const float f4=pt.x-mx,  f5=pt.y-my,  f6=pt.z-mz;
        const float f7=pt.x-ctx, f8=pt.y-cty, f9=pt.z-ctz;
        s0+=f0; s1+=f1; s2+=f2; s3+=f3; s4+=f4;
        s5+=f5; s6+=f6; s7+=f7; s8+=f8; s9+=f9;
#define QACC(idx,i,j) q_##i##_##j = fmaf(f##i, f##j, q_##i##_##j);
        PAIRS(QACC)
#undef QACC
        const int b0 = f2bf(f0), b1 = f2bf(f1), b2 = f2bf(f2), b3 = f2bf(f3),
                  b4 = f2bf(f4), b5 = f2bf(f5), b6 = f2bf(f6), b7 = f2bf(f7),
                  b8 = f2bf(f8), b9 = f2bf(f9);
        const int s8b = __shfl(b8, sub),      s9b = __shfl(b9, sub);
        const int t0 = __shfl(b0, sub + 32), t1 = __shfl(b1, sub + 32),
                  t2 = __shfl(b2, sub + 32), t3 = __shfl(b3, sub + 32),
                  t4 = __shfl(b4, sub + 32), t5 = __shfl(b5, sub + 32),
                  t6 = __shfl(b6, sub + 32), t7 = __shfl(b7, sub + 32);
        short8 a0v;
        a0v[0] = (short)(half ? s8b : b0);
        a0v[1] = (short)(half ? s9b : b1);
        a0v[2] = half ? (short)0 : (short)b2;
        a0v[3] = half ? (short)0 : (short)b3;
        a0v[4] = half ? (short)0 : (short)b4;
        a0v[5] = half ? (short)0 : (short)b5;
        a0v[6] = half ? (short)0 : (short)b6;
        a0v[7] = half ? (short)0 : (short)b7;
        short8 a1v;
        a1v[0] = (short)(half ? b8 : t0);
        a1v[1] = (short)(half ? b9 : t1);
        a1v[2] = half ? (short)0 : (short)t2;
        a1v[3] = half ? (short)0 : (short)t3;
        a1v[4] = half ? (short)0 : (short)t4;
        a1v[5] = half ? (short)0 : (short)t5;
        a1v[6] = half ? (short)0 : (short)t6;
        a1v[7] = half ? (short)0 : (short)t7;
        float16 accA0 = {}, accA1 = {}, accB0 = {}, accB1 = {};
        accA0 = __builtin_amdgcn_mfma_f32_32x32x16_bf16(a0v, bf0, accA0, 0, 0, 0);
        accA1 = __builtin_amdgcn_mfma_f32_32x32x16_bf16(a0v, bf1, accA1, 0, 0, 0);
        accB0 = __builtin_amdgcn_mfma_f32_32x32x16_bf16(a1v, bf0, accB0, 0, 0, 0);
        accB1 = __builtin_amdgcn_mfma_f32_32x32x16_bf16(a1v, bf1, accB1, 0, 0, 0);
        float mA0 = -3.4e38f, mA1 = -3.4e38f, mB0 = -3.4e38f, mB1 = -3.4e38f;
#pragma unroll
        for (int r = 0; r < 16; r++) {
            mA0 = fmaxf(mA0, accA0[r]);  mA1 = fmaxf(mA1, accA1[r]);
            mB0 = fmaxf(mB0, accB0[r]);  mB1 = fmaxf(mB1, accB1[r]);
        }
        mA0 = fmaxf(mA0, __shfl_xor(mA0, 32));  mA1 = fmaxf(mA1, __shfl_xor(mA1, 32));
        mB0 = fmaxf(mB0, __shfl_xor(mB0, 32));  mB1 = fmaxf(mB1, __shfl_xor(mB1, 32));
        pvmax[base * NCHAN + lane]       = half ? mA1 : mA0;
        pvmax[(base + 1) * NCHAN + lane] = half ? mB1 : mB0;
        if (sub == 0) {
            const int cell = cd.y + cd.z * NXC + cd.w;
            atomicMax(&winner[cd.x * NCELLS + cell], p + 1);   // 0 = empty
        }
    }

    __shared__ float lds_part[4][65];
#define RED6(v) { v += __shfl_xor(v,32); v += __shfl_xor(v,16); v += __shfl_xor(v,8); \
                  v += __shfl_xor(v,4);  v += __shfl_xor(v,2);  v += __shfl_xor(v,1); }
    RED6(s0) RED6(s1) RED6(s2) RED6(s3) RED6(s4)
    RED6(s5) RED6(s6) RED6(s7) RED6(s8) RED6(s9)
#define QRED(idx,i,j) RED6(q_##i##_##j)
    PAIRS(QRED)
#undef QRED
#undef RED6
    if (lane == 0) {
        float* dst = &lds_part[wv][0];
        dst[0]=s0; dst[1]=s1; dst[2]=s2; dst[3]=s3; dst[4]=s4;
        dst[5]=s5; dst[6]=s6; dst[7]=s7; dst[8]=s8; dst[9]=s9;
#define QST(idx,i,j) dst[10+idx] = q_##i##_##j;
        PAIRS(QST)
#undef QST
    }
    __syncthreads();
    if (tid < 65) {   // NON-ATOMIC per-block partial (plain store, no RMW)
        const float acc = lds_part[0][tid] + lds_part[1][tid]
                        + lds_part[2][tid] + lds_part[3][tid];
        partial[tid * NBLK + blockIdx.x] = acc;
    }
}

// k_ss: reduce partial[65][NBLK] (260 coalesced 256-float chunk tasks over
// 256 threads, LDS atomics), then fold through W -> per-channel scale/shift.
__global__ void k_ss(const float* __restrict__ partial,
                     const float* __restrict__ W,
                     const float* __restrict__ gamma,
                     const float* __restrict__ beta,
                     float* __restrict__ ss) {
    __shared__ float mom[65];
    const int tid = threadIdx.x;     // 256 threads
    if (tid < 65) mom[tid] = 0.f;
    __syncthreads();
    for (int task = tid; task < 65 * 4; task += 256) {   // 65 moments x 4 chunks
        const int i = task >> 2, ch = task & 3;
        const float4* p4 = (const float4*)(partial + (size_t)i * NBLK) + ch * (NBLK/16);
        float a0=0.f, a1=0.f, a2=0.f, a3=0.f;
#pragma unroll 8
        for (int b = 0; b < NBLK/16; b++) {   // 64 float4 = 256 floats per task
            float4 v = p4[b];
            a0 += v.x; a1 += v.y; a2 += v.z; a3 += v.w;
        }
        atomicAdd(&mom[i], (a0 + a1) + (a2 + a3));
    }
    __syncthreads();
    const int c = tid;
    if (c >= 64) return;
    const float invN = 1.0f / ((float)NPILLARS * (float)MPTS);
    float wv0=W[0*NCHAN+c], wv1=W[1*NCHAN+c], wv2=W[2*NCHAN+c], wv3=W[3*NCHAN+c],
          wv4=W[4*NCHAN+c], wv5=W[5*NCHAN+c], wv6=W[6*NCHAN+c], wv7=W[7*NCHAN+c],
          wv8=W[8*NCHAN+c], wv9=W[9*NCHAN+c];
    float mu = mom[0]*wv0 + mom[1]*wv1 + mom[2]*wv2 + mom[3]*wv3 + mom[4]*wv4
             + mom[5]*wv5 + mom[6]*wv6 + mom[7]*wv7 + mom[8]*wv8 + mom[9]*wv9;
    mu *= invN;
    float e2 = 0.f;
#define QFOLD(idx,i,j) { float tt = mom[10+idx] * wv##i * wv##j; \
                         e2 += (i == j) ? tt : 2.0f * tt; }
    PAIRS(QFOLD)
#undef QFOLD
    e2 *= invN;
    const float var = e2 - mu * mu;
    const float scale = gamma[c] * rsqrtf(var + BN_EPS);
    ss[c] = scale;
    ss[64 + c] = beta[c] - mu * scale;
}

// Expand (R7 form — best measured): 4 cells/thread, vectorized pv row gathers,
// plain float4 channel-plane stores.
__global__ void k_expand(const int* __restrict__ winner,
                         const float* __restrict__ pvmax,
                         const float* __restrict__ ss,
                         float* __restrict__ out) {
    __shared__ float s_sc[64], s_sh[64];
    const int t = threadIdx.x;
    if (t < 64) s_sc[t] = ss[t];
    else if (t < 128) s_sh[t - 64] = ss[t];
    __syncthreads();
    const int idx = blockIdx.x * blockDim.x + t;  // group of 4 cells
    const int total4 = NB * NCELLS / 4;
    if (idx >= total4) return;
    const int b    = (idx << 2) / NCELLS;   // NCELLS % 4 == 0: no straddle
    const int cell = (idx << 2) - b * NCELLS;
    const int4 w = ((const int4*)winner)[idx];
    const float mk0 = (w.x > 0) ? 1.f : 0.f;
    const float mk1 = (w.y > 0) ? 1.f : 0.f;
    const float mk2 = (w.z > 0) ? 1.f : 0.f;
    const float mk3 = (w.w > 0) ? 1.f : 0.f;
    const size_t r0 = (size_t)((w.x > 0) ? w.x - 1 : 0) * NCHAN;
    const size_t r1 = (size_t)((w.y > 0) ? w.y - 1 : 0) * NCHAN;
    const size_t r2 = (size_t)((w.z > 0) ? w.z - 1 : 0) * NCHAN;
    const size_t r3 = (size_t)((w.w > 0) ? w.w - 1 : 0) * NCHAN;
    float* obase = out + (size_t)b * NCHAN * NCELLS + cell;
#pragma unroll 2
    for (int g = 0; g < 16; g++) {          // 4 channels per group
        natf4 a0 = *(const natf4*)(pvmax + r0 + 4*g);
        natf4 a1 = *(const natf4*)(pvmax + r1 + 4*g);
        natf4 a2 = *(const natf4*)(pvmax + r2 + 4*g);
        natf4 a3 = *(const natf4*)(pvmax + r3 + 4*g);
#pragma unroll
        for (int j = 0; j < 4; j++) {
            const int c = 4*g + j;
            const float sc = s_sc[c], sh = s_sh[c];
            natf4 v;
            v.x = mk0 * fmaxf(0.f, fmaf(a0[j], sc, sh));
            v.y = mk1 * fmaxf(0.f, fmaf(a1[j], sc, sh));
            v.z = mk2 * fmaxf(0.f, fmaf(a2[j], sc, sh));
            v.w = mk3 * fmaxf(0.f, fmaf(a3[j], sc, sh));
            *reinterpret_cast<natf4*>(obase + (size_t)c * NCELLS) = v;
        }
    }
}

extern "C" void kernel_launch(void* const* d_in, const int* in_sizes, int n_in,
                              void* d_out, int out_size, void* d_ws, size_t ws_size,
                              hipStream_t stream) {
    const float4* pillars    = (const float4*)d_in[0];
    const int4*   coords     = (const int4*)d_in[1];
    const int*    num_points = (const int*)d_in[2];
    const float*  W          = (const float*)d_in[3];
    const float*  gamma      = (const float*)d_in[4];
    const float*  beta       = (const float*)d_in[5];
    float* out = (float*)d_out;

    char* ws = (char*)d_ws;
    const size_t WIN_BYTES = (size_t)NB * NCELLS * sizeof(int);        // 6.86 MB
    const size_t PV_BYTES  = (size_t)NPILLARS * NCHAN * sizeof(float); // 24.6 MB
    float* ss      = (float*)ws;                         // 128 floats
    int*   winner  = (int*)(ws + 1024);                  // zeroed below (0 = empty)
    float* pvmax   = (float*)(ws + 1024 + WIN_BYTES);
    float* partial = (float*)((char*)pvmax + PV_BYTES);  // 65*NBLK floats = 266 KB

    (void)hipMemsetAsync(winner, 0, WIN_BYTES, stream);  // 0 = empty (p+1 encoding)

    k_fused <<<NBLK, 256, 0, stream>>>(pillars, coords, num_points, W,
                                       pvmax, partial, winner);
    k_ss    <<<1, 256, 0, stream>>>(partial, W, gamma, beta, ss);
    k_expand<<<(NB * NCELLS / 4) / 256, 256, 0, stream>>>(winner, pvmax, ss, out);
}